// Round 7
// baseline (1359.665 us; speedup 1.0000x reference)
//
#include <hip/hip_runtime.h>
#include <hip/hip_bf16.h>
#include <stdint.h>

#define N_TOK 32768
#define DDIM  768
#define FDIM  3072
#define NCOLS (2*FDIM)      // 6144 rows of W1cat
#define BK    64
#define KTILES (DDIM/BK)    // 12
#define NTILES (NCOLS/256)  // 24 column tiles of 256
#define VD_CHUNK 96

typedef __attribute__((ext_vector_type(8))) short bf16x8;
typedef __attribute__((ext_vector_type(4))) float f32x4;

__device__ __forceinline__ unsigned short f2bf(float f) {
  unsigned u = __builtin_bit_cast(unsigned, f);
  unsigned r = (u + 0x7fffu + ((u >> 16) & 1u)) >> 16;
  return (unsigned short)r;
}

__device__ __forceinline__ void gl_lds16(const void* g, void* l) {
  __builtin_amdgcn_global_load_lds(
      (const __attribute__((address_space(1))) unsigned int*)g,
      (__attribute__((address_space(3))) unsigned int*)l, 16, 0, 0);
}

// ---------- W1[:2] fp32 -> bf16 ----------
__global__ __launch_bounds__(256) void cvt_kernel(const float* __restrict__ src,
                                                  unsigned short* __restrict__ dst) {
  size_t i = ((size_t)blockIdx.x * 256 + threadIdx.x) * 4;
  float4 f = *(const float4*)(src + i);
  ushort4 u;
  u.x = f2bf(f.x); u.y = f2bf(f.y); u.z = f2bf(f.z); u.w = f2bf(f.w);
  *(ushort4*)(dst + i) = u;
}

// ---------- vpart[db][k*F+f] = sum_{d in chunk db} W2[k,d,f] * W3[k,0,d] ----------
__global__ __launch_bounds__(256) void vcalc_kernel(const float* __restrict__ W2,
                                                    const float* __restrict__ W3,
                                                    float* __restrict__ vpart) {
  __shared__ float w3s[VD_CHUNK];
  int k  = blockIdx.x / 12;
  int fb = blockIdx.x % 12;
  int db = blockIdx.y;
  if (threadIdx.x < VD_CHUNK) w3s[threadIdx.x] = W3[k*DDIM + db*VD_CHUNK + threadIdx.x];
  __syncthreads();
  int f = fb*256 + threadIdx.x;
  const float* W2k = W2 + (size_t)k*DDIM*FDIM + (size_t)db*VD_CHUNK*FDIM + f;
  float s = 0.f;
  #pragma unroll 8
  for (int d = 0; d < VD_CHUNK; ++d) s += W2k[(size_t)d*FDIM] * w3s[d];
  vpart[(size_t)db*NCOLS + k*FDIM + f] = s;
}

// ---------- v = sum of 8 vpart chunks; block 0 also computes cbuf[k] ----------
__global__ __launch_bounds__(256) void vfinal_kernel(const float* __restrict__ vpart,
                                                     float* __restrict__ v,
                                                     const float* __restrict__ b2,
                                                     const float* __restrict__ W3,
                                                     const float* __restrict__ b3,
                                                     float* __restrict__ cbuf) {
  int f = blockIdx.x*256 + threadIdx.x;
  float s = 0.f;
  #pragma unroll
  for (int db = 0; db < 8; ++db) s += vpart[(size_t)db*NCOLS + f];
  v[f] = s;
  if (blockIdx.x == 0 && threadIdx.x < 128) {
    int k = threadIdx.x >> 6, lane = threadIdx.x & 63;
    float c = 0.f;
    #pragma unroll
    for (int it = 0; it < DDIM/64; ++it) {
      int i = it*64 + lane;
      c += b2[k*DDIM + i] * W3[k*DDIM + i];
    }
    #pragma unroll
    for (int m = 1; m < 64; m <<= 1) c += __shfl_xor(c, m, 64);
    if (lane == 0) cbuf[k] = c + b3[k];
  }
}

// ---------- gate + x->bf16 + W3 dots ----------
__global__ __launch_bounds__(256) void gate_cvt_kernel(
    const float* __restrict__ x, const float* __restrict__ Wg,
    const float* __restrict__ W3, const float* __restrict__ cbuf,
    unsigned short* __restrict__ xbf,
    float* __restrict__ wgt, float* __restrict__ base) {
  int wid  = threadIdx.x >> 6;
  int lane = threadIdx.x & 63;
  int n = blockIdx.x * 4 + wid;
  const float4* xr = (const float4*)(x + (size_t)n * DDIM);
  ushort4* xw = (ushort4*)(xbf + (size_t)n * DDIM);
  float acc[8] = {0,0,0,0,0,0,0,0};
  float d30 = 0.f, d31 = 0.f;
  #pragma unroll
  for (int it = 0; it < DDIM/256; ++it) {
    int i = it*64 + lane;
    float4 xv = xr[i];
    ushort4 u;
    u.x = f2bf(xv.x); u.y = f2bf(xv.y); u.z = f2bf(xv.z); u.w = f2bf(xv.w);
    xw[i] = u;
    #pragma unroll
    for (int e = 0; e < 8; ++e) {
      float4 w = ((const float4*)(Wg + e*DDIM))[i];
      acc[e] += xv.x*w.x + xv.y*w.y + xv.z*w.z + xv.w*w.w;
    }
    float4 wa = ((const float4*)W3)[i];
    d30 += xv.x*wa.x + xv.y*wa.y + xv.z*wa.z + xv.w*wa.w;
    float4 wb = ((const float4*)(W3 + DDIM))[i];
    d31 += xv.x*wb.x + xv.y*wb.y + xv.z*wb.z + xv.w*wb.w;
  }
  #pragma unroll
  for (int m = 1; m < 64; m <<= 1) {
    #pragma unroll
    for (int e = 0; e < 8; ++e) acc[e] += __shfl_xor(acc[e], m, 64);
    d30 += __shfl_xor(d30, m, 64);
    d31 += __shfl_xor(d31, m, 64);
  }
  if (lane == 0) {
    float l1 = acc[0]; int a1 = 0;
    #pragma unroll
    for (int e = 1; e < 8; ++e) if (acc[e] > l1) { l1 = acc[e]; a1 = e; }
    float l2 = -3.4e38f;
    #pragma unroll
    for (int e = 0; e < 8; ++e) if (e != a1 && acc[e] > l2) l2 = acc[e];
    float w0 = 1.f / (1.f + __expf(l2 - l1));
    float w1 = 1.f - w0;
    wgt[2*n]   = w0;
    wgt[2*n+1] = w1;
    base[n] = w0 * (d30 + cbuf[0]) + w1 * (d31 + cbuf[1]);
  }
}

// ---------- fused GEMM (R2 structure) + ablation probes ----------
// MODE 0 = full (real output). MODE 1 = NOSTAGE (prologue stages only; loop =
// ds_read+MFMA+sync). MODE 2 = STAGEONLY (stages+vmcnt+sync, no reads/MFMA).
// MODE 3 = MFMAONLY (frags hoisted to regs; loop = MFMA+sync).
// Probes write garbage to scratch; only MODE 0 feeds the real pipeline.
template<int MODE>
__global__ __launch_bounds__(512, 2) void gemm_t(
    const unsigned short* __restrict__ A,   // 32768 x 768 bf16
    const unsigned short* __restrict__ B,   // 6144 x 768 bf16 (B^T layout)
    const float* __restrict__ b1,
    const float* __restrict__ v,
    float* __restrict__ part) {             // 24 x 32768
  __shared__ __align__(16) char smem[131072];   // 2 x 64KB

  const int tid  = threadIdx.x;
  const int lane = tid & 63, wid = tid >> 6;
  const int wm = wid >> 2, wn = wid & 3;        // 2M x 4N waves, per-wave C = 128x64
  const int q  = lane >> 4, cl = lane & 15;
  const int bn = blockIdx.x;     // 0..23
  const int bm = blockIdx.y;     // 0..127

  const unsigned short* Ab = A + (size_t)bm * 256 * DDIM;
  const unsigned short* Bb = B + (size_t)bn * 256 * DDIM;

  // staging source: thread (wid,lane) of issue j fetches G[(j*8+wid)*16 + cl][kslot q]
  // -> lands (linear dest) at fragment block (j*8+wid), offset lane*16.
  const size_t srow = (size_t)(wid*16 + cl) * DDIM + q*8;

  const int lb = lane * 16;
  const int aBase = wm*8192 + lb;           // + h*4096 + m*1024 (+ks*32768)
  const int bBase = 16384 + wn*4096 + lb;   // + n*1024 (+ks*32768)

  f32x4 zero = {0.f, 0.f, 0.f, 0.f};
  f32x4 acc[8][4];
  #pragma unroll
  for (int i = 0; i < 8; ++i)
    #pragma unroll
    for (int j = 0; j < 4; ++j) acc[i][j] = zero;

  auto stageA = [&](int t, int ks) {
    char* dst = smem + (t & 1) * 65536 + ks * 32768;
    const unsigned short* s0 = Ab + srow + t*BK + ks*32;
    gl_lds16(s0,            dst + wid*1024);
    gl_lds16(s0 + 128*DDIM, dst + 8192 + wid*1024);
  };
  auto stageB = [&](int t, int ks) {
    char* dst = smem + (t & 1) * 65536 + ks * 32768 + 16384;
    const unsigned short* s0 = Bb + srow + t*BK + ks*32;
    gl_lds16(s0,            dst + wid*1024);
    gl_lds16(s0 + 128*DDIM, dst + 8192 + wid*1024);
  };

  // prologue (all modes): 6 regions in flight; retire first 2
  stageA(0, 0); stageB(0, 0);
  stageA(0, 1); stageB(0, 1);
  stageA(1, 0); stageB(1, 0);
  asm volatile("s_waitcnt vmcnt(8)" ::: "memory");
  __builtin_amdgcn_s_barrier();
  __builtin_amdgcn_sched_barrier(0);

  bf16x8 afh[4], bfh[4];   // MODE 3: hoisted fragments
  if constexpr (MODE == 3) {
    #pragma unroll
    for (int n = 0; n < 4; ++n) bfh[n] = *(const bf16x8*)(smem + bBase + n*1024);
    #pragma unroll
    for (int m = 0; m < 4; ++m) afh[m] = *(const bf16x8*)(smem + aBase + m*1024);
    asm volatile("s_waitcnt lgkmcnt(0)" ::: "memory");
    __builtin_amdgcn_sched_barrier(0);
  }

  #pragma unroll
  for (int kt = 0; kt < KTILES; ++kt) {
    const char* ct = smem + (kt & 1) * 65536;
    bf16x8 af[4], bfr[4];

    // ---- phase 0: ks=0, M-half 0 ----
    if constexpr (MODE == 0 || MODE == 1) {
      #pragma unroll
      for (int n = 0; n < 4; ++n) bfr[n] = *(const bf16x8*)(ct + bBase + n*1024);
      #pragma unroll
      for (int m = 0; m < 4; ++m) af[m] = *(const bf16x8*)(ct + aBase + m*1024);
    }
    if constexpr (MODE == 0 || MODE == 2) { if (kt <= 10) stageA(kt + 1, 1); }
    __builtin_amdgcn_s_barrier();
    asm volatile("s_waitcnt lgkmcnt(0)" ::: "memory");
    __builtin_amdgcn_s_setprio(1);
    if constexpr (MODE == 0 || MODE == 1) {
      #pragma unroll
      for (int m = 0; m < 4; ++m)
        #pragma unroll
        for (int n = 0; n < 4; ++n)
          acc[m][n] = __builtin_amdgcn_mfma_f32_16x16x32_bf16(af[m], bfr[n], acc[m][n], 0, 0, 0);
    } else if constexpr (MODE == 3) {
      #pragma unroll
      for (int m = 0; m < 4; ++m)
        #pragma unroll
        for (int n = 0; n < 4; ++n)
          acc[m][n] = __builtin_amdgcn_mfma_f32_16x16x32_bf16(afh[m], bfh[n], acc[m][n], 0, 0, 0);
    }
    __builtin_amdgcn_s_setprio(0);
    __builtin_amdgcn_s_barrier();

    // ---- phase 1: ks=0, M-half 1 ----
    if constexpr (MODE == 0 || MODE == 1) {
      #pragma unroll
      for (int m = 0; m < 4; ++m) af[m] = *(const bf16x8*)(ct + aBase + 4096 + m*1024);
    }
    if constexpr (MODE == 0 || MODE == 2) { if (kt <= 10) stageB(kt + 1, 1); }
    __builtin_amdgcn_s_barrier();
    asm volatile("s_waitcnt lgkmcnt(0)" ::: "memory");
    __builtin_amdgcn_s_setprio(1);
    if constexpr (MODE == 0 || MODE == 1) {
      #pragma unroll
      for (int m = 0; m < 4; ++m)
        #pragma unroll
        for (int n = 0; n < 4; ++n)
          acc[4 + m][n] = __builtin_amdgcn_mfma_f32_16x16x32_bf16(af[m], bfr[n], acc[4 + m][n], 0, 0, 0);
    } else if constexpr (MODE == 3) {
      #pragma unroll
      for (int m = 0; m < 4; ++m)
        #pragma unroll
        for (int n = 0; n < 4; ++n)
          acc[4 + m][n] = __builtin_amdgcn_mfma_f32_16x16x32_bf16(afh[m], bfh[n], acc[4 + m][n], 0, 0, 0);
    }
    __builtin_amdgcn_s_setprio(0);
    if (kt <= 10) { asm volatile("s_waitcnt vmcnt(8)" ::: "memory"); }
    else          { asm volatile("s_waitcnt vmcnt(0)" ::: "memory"); }
    __builtin_amdgcn_s_barrier();
    __builtin_amdgcn_sched_barrier(0);

    // ---- phase 2: ks=1, M-half 0 ----
    if constexpr (MODE == 0 || MODE == 1) {
      #pragma unroll
      for (int n = 0; n < 4; ++n) bfr[n] = *(const bf16x8*)(ct + 32768 + bBase + n*1024);
      #pragma unroll
      for (int m = 0; m < 4; ++m) af[m] = *(const bf16x8*)(ct + 32768 + aBase + m*1024);
    }
    if constexpr (MODE == 0 || MODE == 2) { if (kt <= 9) stageA(kt + 2, 0); }
    __builtin_amdgcn_s_barrier();
    asm volatile("s_waitcnt lgkmcnt(0)" ::: "memory");
    __builtin_amdgcn_s_setprio(1);
    if constexpr (MODE == 0 || MODE == 1) {
      #pragma unroll
      for (int m = 0; m < 4; ++m)
        #pragma unroll
        for (int n = 0; n < 4; ++n)
          acc[m][n] = __builtin_amdgcn_mfma_f32_16x16x32_bf16(af[m], bfr[n], acc[m][n], 0, 0, 0);
    } else if constexpr (MODE == 3) {
      #pragma unroll
      for (int m = 0; m < 4; ++m)
        #pragma unroll
        for (int n = 0; n < 4; ++n)
          acc[m][n] = __builtin_amdgcn_mfma_f32_16x16x32_bf16(afh[m], bfh[n], acc[m][n], 0, 0, 0);
    }
    __builtin_amdgcn_s_setprio(0);
    __builtin_amdgcn_s_barrier();

    // ---- phase 3: ks=1, M-half 1 ----
    if constexpr (MODE == 0 || MODE == 1) {
      #pragma unroll
      for (int m = 0; m < 4; ++m) af[m] = *(const bf16x8*)(ct + 32768 + aBase + 4096 + m*1024);
    }
    if constexpr (MODE == 0 || MODE == 2) { if (kt <= 9) stageB(kt + 2, 0); }
    __builtin_amdgcn_s_barrier();
    asm volatile("s_waitcnt lgkmcnt(0)" ::: "memory");
    __builtin_amdgcn_s_setprio(1);
    if constexpr (MODE == 0 || MODE == 1) {
      #pragma unroll
      for (int m = 0; m < 4; ++m)
        #pragma unroll
        for (int n = 0; n < 4; ++n)
          acc[4 + m][n] = __builtin_amdgcn_mfma_f32_16x16x32_bf16(af[m], bfr[n], acc[4 + m][n], 0, 0, 0);
    } else if constexpr (MODE == 3) {
      #pragma unroll
      for (int m = 0; m < 4; ++m)
        #pragma unroll
        for (int n = 0; n < 4; ++n)
          acc[4 + m][n] = __builtin_amdgcn_mfma_f32_16x16x32_bf16(afh[m], bfh[n], acc[4 + m][n], 0, 0, 0);
    }
    __builtin_amdgcn_s_setprio(0);
    if (kt <= 9)        { asm volatile("s_waitcnt vmcnt(8)" ::: "memory"); }
    else if (kt == 10)  { asm volatile("s_waitcnt vmcnt(4)" ::: "memory"); }
    else                { asm volatile("s_waitcnt vmcnt(0)" ::: "memory"); }
    __builtin_amdgcn_s_barrier();
    __builtin_amdgcn_sched_barrier(0);
  }

  // epilogue (all modes): relu(acc + b1[col]) * v[col], reduce 256 cols per row
  float vv[4], bb[4];
  #pragma unroll
  for (int n = 0; n < 4; ++n) {
    int cg = bn*256 + wn*64 + n*16 + cl;
    vv[n] = v[cg];
    bb[n] = b1[cg];
  }
  float* red = (float*)smem;
  #pragma unroll
  for (int mt = 0; mt < 8; ++mt) {
    #pragma unroll
    for (int rr = 0; rr < 4; ++rr) {
      float s = 0.f;
      #pragma unroll
      for (int n = 0; n < 4; ++n) {
        float val = acc[mt][n][rr] + bb[n];
        s += fmaxf(val, 0.f) * vv[n];
      }
      #pragma unroll
      for (int msk = 1; msk < 16; msk <<= 1) s += __shfl_xor(s, msk, 64);
      if (cl == 0) red[(wm*128 + mt*16 + q*4 + rr)*4 + wn] = s;
    }
  }
  __syncthreads();
  if (tid < 256) {
    float r4 = red[tid*4] + red[tid*4+1] + red[tid*4+2] + red[tid*4+3];
    part[(size_t)bn * N_TOK + (size_t)bm*256 + tid] = r4;
  }
}

// ---------- final combine ----------
__global__ __launch_bounds__(256) void final_kernel(const float* __restrict__ part,
                                                    const float* __restrict__ wgt,
                                                    const float* __restrict__ base,
                                                    float* __restrict__ out) {
  int n = blockIdx.x * 256 + threadIdx.x;
  float s0 = 0.f, s1 = 0.f;
  #pragma unroll
  for (int t = 0; t < 12; ++t) s0 += part[(size_t)t*N_TOK + n];
  #pragma unroll
  for (int t = 12; t < 24; ++t) s1 += part[(size_t)t*N_TOK + n];
  out[n] = base[n] + wgt[2*n]*s0 + wgt[2*n+1]*s1;
}

extern "C" void kernel_launch(void* const* d_in, const int* in_sizes, int n_in,
                              void* d_out, int out_size, void* d_ws, size_t ws_size,
                              hipStream_t stream) {
  const float* x  = (const float*)d_in[0];
  const float* Wg = (const float*)d_in[1];
  const float* W1 = (const float*)d_in[2];
  const float* b1 = (const float*)d_in[3];
  const float* W2 = (const float*)d_in[4];
  const float* b2 = (const float*)d_in[5];
  const float* W3 = (const float*)d_in[6];
  const float* b3 = (const float*)d_in[7];
  float* out = (float*)d_out;

  char* ws = (char*)d_ws;
  size_t off = 0;
  auto alloc = [&](size_t bytes) -> char* {
    char* p = ws + off;
    off += (bytes + 255) & ~(size_t)255;
    return p;
  };
  unsigned short* xbf  = (unsigned short*)alloc((size_t)N_TOK * DDIM * 2);   // 48 MB
  unsigned short* w1bf = (unsigned short*)alloc((size_t)NCOLS * DDIM * 2);   // 9 MB
  float* vpart = (float*)alloc((size_t)8 * NCOLS * 4);
  float* v     = (float*)alloc((size_t)NCOLS * 4);
  float* cbuf  = (float*)alloc(64);
  float* wgt   = (float*)alloc((size_t)N_TOK * 2 * 4);
  float* base  = (float*)alloc((size_t)N_TOK * 4);
  float* part  = (float*)alloc((size_t)NTILES * N_TOK * 4);                  // 3.1 MB
  float* pscr  = (float*)alloc((size_t)NTILES * N_TOK * 4);                  // probe scratch
  if (off > ws_size) return;

  cvt_kernel<<<(NCOLS*DDIM)/1024, 256, 0, stream>>>(W1, w1bf);
  vcalc_kernel<<<dim3(24, 8), 256, 0, stream>>>(W2, W3, vpart);
  vfinal_kernel<<<NCOLS/256, 256, 0, stream>>>(vpart, v, b2, W3, b3, cbuf);
  gate_cvt_kernel<<<N_TOK/4, 256, 0, stream>>>(x, Wg, W3, cbuf, xbf, wgt, base);
  gemm_t<0><<<dim3(NTILES, N_TOK/256), 512, 0, stream>>>(xbf, w1bf, b1, v, part);
  final_kernel<<<N_TOK/256, 256, 0, stream>>>(part, wgt, base, out);

  // ---- ablation probes (scratch output; rocprof separates by template name) ----
  gemm_t<1><<<dim3(NTILES, N_TOK/256), 512, 0, stream>>>(xbf, w1bf, b1, v, pscr);
  gemm_t<2><<<dim3(NTILES, N_TOK/256), 512, 0, stream>>>(xbf, w1bf, b1, v, pscr);
  gemm_t<3><<<dim3(NTILES, N_TOK/256), 512, 0, stream>>>(xbf, w1bf, b1, v, pscr);
}

// Round 8
// 607.130 us; speedup vs baseline: 2.2395x; 2.2395x over previous
//
#include <hip/hip_runtime.h>
#include <hip/hip_bf16.h>
#include <stdint.h>

#define N_TOK 32768
#define DDIM  768
#define FDIM  3072
#define NCOLS (2*FDIM)      // 6144 rows of W1cat
#define BK    64
#define KTILES (DDIM/BK)    // 12
#define NTILES (NCOLS/256)  // 24 column tiles of 256
#define VD_CHUNK 96

// prep_kernel block ranges
#define CVT_BLOCKS   4608   // (NCOLS*DDIM)/1024
#define VCALC_BLOCKS 192    // 2 experts x 12 fblocks x 8 dchunks
#define GATE_BLOCKS  8192   // N_TOK/4
#define PREP_BLOCKS  (CVT_BLOCKS + VCALC_BLOCKS + 1 + GATE_BLOCKS)

typedef __attribute__((ext_vector_type(8))) short bf16x8;
typedef __attribute__((ext_vector_type(4))) float f32x4;

__device__ __forceinline__ unsigned short f2bf(float f) {
  unsigned u = __builtin_bit_cast(unsigned, f);
  unsigned r = (u + 0x7fffu + ((u >> 16) & 1u)) >> 16;
  return (unsigned short)r;
}

__device__ __forceinline__ void gl_lds16(const void* g, void* l) {
  __builtin_amdgcn_global_load_lds(
      (const __attribute__((address_space(1))) unsigned int*)g,
      (__attribute__((address_space(3))) unsigned int*)l, 16, 0, 0);
}

// ---------- fused prep: cvt W1->bf16 | v via atomicAdd | cbuf | gate+x->bf16 ----------
// All slices are mutually independent (no cross-block deps): gate writes base WITHOUT
// the cbuf term; final_kernel adds w0*cbuf0 + w1*cbuf1 instead.
__global__ __launch_bounds__(256) void prep_kernel(
    const float* __restrict__ W1, unsigned short* __restrict__ w1bf,
    const float* __restrict__ W2, const float* __restrict__ W3,
    float* __restrict__ v,
    const float* __restrict__ b2, const float* __restrict__ b3,
    float* __restrict__ cbuf,
    const float* __restrict__ x, const float* __restrict__ Wg,
    unsigned short* __restrict__ xbf,
    float* __restrict__ wgt, float* __restrict__ base) {
  __shared__ float w3s[VD_CHUNK];
  const int b = blockIdx.x;

  if (b < CVT_BLOCKS) {
    // ---- W1[:2] fp32 -> bf16 ----
    size_t i = ((size_t)b * 256 + threadIdx.x) * 4;
    float4 f = *(const float4*)(W1 + i);
    ushort4 u;
    u.x = f2bf(f.x); u.y = f2bf(f.y); u.z = f2bf(f.z); u.w = f2bf(f.w);
    *(ushort4*)(w1bf + i) = u;
    return;
  }
  if (b < CVT_BLOCKS + VCALC_BLOCKS) {
    // ---- v[k*F+f] += sum_{d in chunk db} W2[k,d,f] * W3[k,0,d] ----
    int vb = b - CVT_BLOCKS;          // 0..191
    int k  = vb / 96;
    int fb = (vb % 96) / 8;
    int db = vb % 8;
    if (threadIdx.x < VD_CHUNK) w3s[threadIdx.x] = W3[k*DDIM + db*VD_CHUNK + threadIdx.x];
    __syncthreads();
    int f = fb*256 + threadIdx.x;
    const float* W2k = W2 + (size_t)k*DDIM*FDIM + (size_t)db*VD_CHUNK*FDIM + f;
    float s = 0.f;
    #pragma unroll 8
    for (int d = 0; d < VD_CHUNK; ++d) s += W2k[(size_t)d*FDIM] * w3s[d];
    atomicAdd(&v[k*FDIM + f], s);
    return;
  }
  if (b == CVT_BLOCKS + VCALC_BLOCKS) {
    // ---- cbuf[k] = b2[k,:]·W3[k,:] + b3[k] ----
    if (threadIdx.x < 128) {
      int k = threadIdx.x >> 6, lane = threadIdx.x & 63;
      float c = 0.f;
      #pragma unroll
      for (int it = 0; it < DDIM/64; ++it) {
        int i = it*64 + lane;
        c += b2[k*DDIM + i] * W3[k*DDIM + i];
      }
      #pragma unroll
      for (int m = 1; m < 64; m <<= 1) c += __shfl_xor(c, m, 64);
      if (lane == 0) cbuf[k] = c + b3[k];
    }
    return;
  }
  // ---- gate + x->bf16 + W3 dots (base WITHOUT cbuf term) ----
  int gb   = b - (CVT_BLOCKS + VCALC_BLOCKS + 1);
  int wid  = threadIdx.x >> 6;
  int lane = threadIdx.x & 63;
  int n = gb * 4 + wid;
  const float4* xr = (const float4*)(x + (size_t)n * DDIM);
  ushort4* xw = (ushort4*)(xbf + (size_t)n * DDIM);
  float acc[8] = {0,0,0,0,0,0,0,0};
  float d30 = 0.f, d31 = 0.f;
  #pragma unroll
  for (int it = 0; it < DDIM/256; ++it) {
    int i = it*64 + lane;
    float4 xv = xr[i];
    ushort4 u;
    u.x = f2bf(xv.x); u.y = f2bf(xv.y); u.z = f2bf(xv.z); u.w = f2bf(xv.w);
    xw[i] = u;
    #pragma unroll
    for (int e = 0; e < 8; ++e) {
      float4 w = ((const float4*)(Wg + e*DDIM))[i];
      acc[e] += xv.x*w.x + xv.y*w.y + xv.z*w.z + xv.w*w.w;
    }
    float4 wa = ((const float4*)W3)[i];
    d30 += xv.x*wa.x + xv.y*wa.y + xv.z*wa.z + xv.w*wa.w;
    float4 wb = ((const float4*)(W3 + DDIM))[i];
    d31 += xv.x*wb.x + xv.y*wb.y + xv.z*wb.z + xv.w*wb.w;
  }
  #pragma unroll
  for (int m = 1; m < 64; m <<= 1) {
    #pragma unroll
    for (int e = 0; e < 8; ++e) acc[e] += __shfl_xor(acc[e], m, 64);
    d30 += __shfl_xor(d30, m, 64);
    d31 += __shfl_xor(d31, m, 64);
  }
  if (lane == 0) {
    float l1 = acc[0]; int a1 = 0;
    #pragma unroll
    for (int e = 1; e < 8; ++e) if (acc[e] > l1) { l1 = acc[e]; a1 = e; }
    float l2 = -3.4e38f;
    #pragma unroll
    for (int e = 0; e < 8; ++e) if (e != a1 && acc[e] > l2) l2 = acc[e];
    float w0 = 1.f / (1.f + __expf(l2 - l1));
    float w1 = 1.f - w0;
    wgt[2*n]   = w0;
    wgt[2*n+1] = w1;
    base[n] = w0 * d30 + w1 * d31;
  }
}

// ---------- fused GEMM, 256x256 tile, BK=64, counted-lgkmcnt overlap windows ----------
// part[bn][row] = sum_{col in tile bn(256)} relu(X@W1cat^T + b1)[row][col] * v[col]
// LDS per buffer (64KB): Ak0 @0, Bk0 @16K, Ak1 @32K, Bk1 @48K (each 16KB).
// Fragment-order layout: block bb (1KB) holds G[bb*16 + (lane&15)][kslot lane>>4]
//   at offset lane*16 -> all ds_read_b128 stride-1 conflict-free.
// Window (per ks): issue ALL 12 ds_reads + stage; lgkmcnt(4) -> MFMA cluster 0
// runs WHILE the last 4 reads (a1) drain; lgkmcnt(0) -> cluster 1. This is the
// first variant where LDS drain overlaps MFMA within a wave (R1/R2/R5 all did a
// full lgkmcnt(0) drain before any MFMA). sched_barrier(0) after each counted
// wait per rule #18 (stops MFMA hoisting above the wait).
// vmcnt(8) keeps 4 regions in flight; winA(t) stages ks=1(t+1), winB(t) stages ks=0(t+2).
__global__ __launch_bounds__(512, 2) void gemm_kernel(
    const unsigned short* __restrict__ A,   // 32768 x 768 bf16
    const unsigned short* __restrict__ B,   // 6144 x 768 bf16 (B^T layout)
    const float* __restrict__ b1,
    const float* __restrict__ v,
    float* __restrict__ part) {             // 24 x 32768
  __shared__ __align__(16) char smem[131072];   // 2 x 64KB

  const int tid  = threadIdx.x;
  const int lane = tid & 63, wid = tid >> 6;
  const int wm = wid >> 2, wn = wid & 3;        // 2M x 4N waves, per-wave C = 128x64
  const int q  = lane >> 4, cl = lane & 15;
  const int bn = blockIdx.x;     // 0..23
  const int bm = blockIdx.y;     // 0..127

  const unsigned short* Ab = A + (size_t)bm * 256 * DDIM;
  const unsigned short* Bb = B + (size_t)bn * 256 * DDIM;

  // staging source: thread (wid,lane) of issue j fetches G[(j*8+wid)*16 + cl][kslot q]
  // -> lands (linear dest) at fragment block (j*8+wid), offset lane*16.
  const size_t srow = (size_t)(wid*16 + cl) * DDIM + q*8;

  const int lb = lane * 16;
  const int aBase = wm*8192 + lb;           // + h*4096 + m*1024 (+ks*32768)
  const int bBase = 16384 + wn*4096 + lb;   // + n*1024 (+ks*32768)

  f32x4 zero = {0.f, 0.f, 0.f, 0.f};
  f32x4 acc[8][4];
  #pragma unroll
  for (int i = 0; i < 8; ++i)
    #pragma unroll
    for (int j = 0; j < 4; ++j) acc[i][j] = zero;

  auto stageA = [&](int t, int ks) {
    char* dst = smem + (t & 1) * 65536 + ks * 32768;
    const unsigned short* s0 = Ab + srow + t*BK + ks*32;
    gl_lds16(s0,            dst + wid*1024);
    gl_lds16(s0 + 128*DDIM, dst + 8192 + wid*1024);
  };
  auto stageB = [&](int t, int ks) {
    char* dst = smem + (t & 1) * 65536 + ks * 32768 + 16384;
    const unsigned short* s0 = Bb + srow + t*BK + ks*32;
    gl_lds16(s0,            dst + wid*1024);
    gl_lds16(s0 + 128*DDIM, dst + 8192 + wid*1024);
  };

  // prologue: 6 regions issued; vmcnt(8) retires Ak0(0),Bk0(0)
  stageA(0, 0); stageB(0, 0);
  stageA(0, 1); stageB(0, 1);
  stageA(1, 0); stageB(1, 0);
  asm volatile("s_waitcnt vmcnt(8)" ::: "memory");
  __builtin_amdgcn_s_barrier();
  __builtin_amdgcn_sched_barrier(0);

  #pragma unroll
  for (int kt = 0; kt < KTILES; ++kt) {
    const char* ct = smem + (kt & 1) * 65536;
    bf16x8 a0[4], a1[4], bfr[4];

    // ==== window A: ks=0 ====
    #pragma unroll
    for (int n = 0; n < 4; ++n) bfr[n] = *(const bf16x8*)(ct + bBase + n*1024);
    #pragma unroll
    for (int m = 0; m < 4; ++m) a0[m] = *(const bf16x8*)(ct + aBase + m*1024);
    #pragma unroll
    for (int m = 0; m < 4; ++m) a1[m] = *(const bf16x8*)(ct + aBase + 4096 + m*1024);
    if (kt <= 10) { stageA(kt + 1, 1); stageB(kt + 1, 1); }
    asm volatile("s_waitcnt lgkmcnt(4)" ::: "memory");   // bfr + a0 complete
    __builtin_amdgcn_sched_barrier(0);
    __builtin_amdgcn_s_setprio(1);
    #pragma unroll
    for (int m = 0; m < 4; ++m)
      #pragma unroll
      for (int n = 0; n < 4; ++n)
        acc[m][n] = __builtin_amdgcn_mfma_f32_16x16x32_bf16(a0[m], bfr[n], acc[m][n], 0, 0, 0);
    __builtin_amdgcn_s_setprio(0);
    asm volatile("s_waitcnt lgkmcnt(0)" ::: "memory");   // a1 complete (drained under cluster 0)
    __builtin_amdgcn_sched_barrier(0);
    __builtin_amdgcn_s_setprio(1);
    #pragma unroll
    for (int m = 0; m < 4; ++m)
      #pragma unroll
      for (int n = 0; n < 4; ++n)
        acc[4 + m][n] = __builtin_amdgcn_mfma_f32_16x16x32_bf16(a1[m], bfr[n], acc[4 + m][n], 0, 0, 0);
    __builtin_amdgcn_s_setprio(0);
    if (kt <= 10) { asm volatile("s_waitcnt vmcnt(8)" ::: "memory"); }
    else          { asm volatile("s_waitcnt vmcnt(0)" ::: "memory"); }
    __builtin_amdgcn_s_barrier();
    __builtin_amdgcn_sched_barrier(0);

    // ==== window B: ks=1 ====
    #pragma unroll
    for (int n = 0; n < 4; ++n) bfr[n] = *(const bf16x8*)(ct + 32768 + bBase + n*1024);
    #pragma unroll
    for (int m = 0; m < 4; ++m) a0[m] = *(const bf16x8*)(ct + 32768 + aBase + m*1024);
    #pragma unroll
    for (int m = 0; m < 4; ++m) a1[m] = *(const bf16x8*)(ct + 32768 + aBase + 4096 + m*1024);
    if (kt <= 9) { stageA(kt + 2, 0); stageB(kt + 2, 0); }
    asm volatile("s_waitcnt lgkmcnt(4)" ::: "memory");
    __builtin_amdgcn_sched_barrier(0);
    __builtin_amdgcn_s_setprio(1);
    #pragma unroll
    for (int m = 0; m < 4; ++m)
      #pragma unroll
      for (int n = 0; n < 4; ++n)
        acc[m][n] = __builtin_amdgcn_mfma_f32_16x16x32_bf16(a0[m], bfr[n], acc[m][n], 0, 0, 0);
    __builtin_amdgcn_s_setprio(0);
    asm volatile("s_waitcnt lgkmcnt(0)" ::: "memory");
    __builtin_amdgcn_sched_barrier(0);
    __builtin_amdgcn_s_setprio(1);
    #pragma unroll
    for (int m = 0; m < 4; ++m)
      #pragma unroll
      for (int n = 0; n < 4; ++n)
        acc[4 + m][n] = __builtin_amdgcn_mfma_f32_16x16x32_bf16(a1[m], bfr[n], acc[4 + m][n], 0, 0, 0);
    __builtin_amdgcn_s_setprio(0);
    if (kt <= 9)       { asm volatile("s_waitcnt vmcnt(8)" ::: "memory"); }
    else if (kt == 10) { asm volatile("s_waitcnt vmcnt(4)" ::: "memory"); }
    __builtin_amdgcn_s_barrier();
    __builtin_amdgcn_sched_barrier(0);
  }

  // epilogue: relu(acc + b1[col]) * v[col], reduce 256 cols per row
  float vv[4], bb[4];
  #pragma unroll
  for (int n = 0; n < 4; ++n) {
    int cg = bn*256 + wn*64 + n*16 + cl;
    vv[n] = v[cg];
    bb[n] = b1[cg];
  }
  float* red = (float*)smem;   // 4KB at smem+0 (buf0.Ak0; all reads done)
  #pragma unroll
  for (int mt = 0; mt < 8; ++mt) {
    #pragma unroll
    for (int rr = 0; rr < 4; ++rr) {
      float s = 0.f;
      #pragma unroll
      for (int n = 0; n < 4; ++n) {
        float val = acc[mt][n][rr] + bb[n];
        s += fmaxf(val, 0.f) * vv[n];
      }
      #pragma unroll
      for (int msk = 1; msk < 16; msk <<= 1) s += __shfl_xor(s, msk, 64);
      if (cl == 0) red[(wm*128 + mt*16 + q*4 + rr)*4 + wn] = s;
    }
  }
  __syncthreads();
  if (tid < 256) {
    float r4 = red[tid*4] + red[tid*4+1] + red[tid*4+2] + red[tid*4+3];
    part[(size_t)bn * N_TOK + (size_t)bm*256 + tid] = r4;
  }
}

// ---------- final combine (adds the cbuf term moved out of gate) ----------
__global__ __launch_bounds__(256) void final_kernel(const float* __restrict__ part,
                                                    const float* __restrict__ wgt,
                                                    const float* __restrict__ base,
                                                    const float* __restrict__ cbuf,
                                                    float* __restrict__ out) {
  int n = blockIdx.x * 256 + threadIdx.x;
  float s0 = 0.f, s1 = 0.f;
  #pragma unroll
  for (int t = 0; t < 12; ++t) s0 += part[(size_t)t*N_TOK + n];
  #pragma unroll
  for (int t = 12; t < 24; ++t) s1 += part[(size_t)t*N_TOK + n];
  out[n] = base[n] + wgt[2*n]*(s0 + cbuf[0]) + wgt[2*n+1]*(s1 + cbuf[1]);
}

extern "C" void kernel_launch(void* const* d_in, const int* in_sizes, int n_in,
                              void* d_out, int out_size, void* d_ws, size_t ws_size,
                              hipStream_t stream) {
  const float* x  = (const float*)d_in[0];
  const float* Wg = (const float*)d_in[1];
  const float* W1 = (const float*)d_in[2];
  const float* b1 = (const float*)d_in[3];
  const float* W2 = (const float*)d_in[4];
  const float* b2 = (const float*)d_in[5];
  const float* W3 = (const float*)d_in[6];
  const float* b3 = (const float*)d_in[7];
  float* out = (float*)d_out;

  char* ws = (char*)d_ws;
  size_t off = 0;
  auto alloc = [&](size_t bytes) -> char* {
    char* p = ws + off;
    off += (bytes + 255) & ~(size_t)255;
    return p;
  };
  unsigned short* xbf  = (unsigned short*)alloc((size_t)N_TOK * DDIM * 2);   // 48 MB
  unsigned short* w1bf = (unsigned short*)alloc((size_t)NCOLS * DDIM * 2);   // 9 MB
  float* v     = (float*)alloc((size_t)NCOLS * 4);
  float* cbuf  = (float*)alloc(64);
  float* wgt   = (float*)alloc((size_t)N_TOK * 2 * 4);
  float* base  = (float*)alloc((size_t)N_TOK * 4);
  float* part  = (float*)alloc((size_t)NTILES * N_TOK * 4);                  // 3.1 MB
  if (off > ws_size) return;

  hipMemsetAsync(v, 0, (size_t)NCOLS * 4, stream);
  prep_kernel<<<PREP_BLOCKS, 256, 0, stream>>>(W1, w1bf, W2, W3, v, b2, b3, cbuf,
                                               x, Wg, xbf, wgt, base);
  gemm_kernel<<<dim3(NTILES, N_TOK/256), 512, 0, stream>>>(xbf, w1bf, b1, v, part);
  final_kernel<<<N_TOK/256, 256, 0, stream>>>(part, wgt, base, cbuf, out);
}

// Round 9
// 603.687 us; speedup vs baseline: 2.2523x; 1.0057x over previous
//
#include <hip/hip_runtime.h>
#include <hip/hip_bf16.h>
#include <stdint.h>

#define N_TOK 32768
#define DDIM  768
#define FDIM  3072
#define NCOLS (2*FDIM)      // 6144 rows of W1cat
#define BK    32
#define KTILES (DDIM/BK)    // 24
#define NTILES (NCOLS/256)  // 24 column tiles of 256
#define VD_CHUNK 96

// prep_kernel block ranges
#define CVT_BLOCKS   4608   // (NCOLS*DDIM)/1024
#define VCALC_BLOCKS 192    // 2 experts x 12 fblocks x 8 dchunks
#define GATE_BLOCKS  8192   // N_TOK/4
#define PREP_BLOCKS  (CVT_BLOCKS + VCALC_BLOCKS + 1 + GATE_BLOCKS)

typedef __attribute__((ext_vector_type(8))) short bf16x8;
typedef __attribute__((ext_vector_type(4))) float f32x4;

__device__ __forceinline__ unsigned short f2bf(float f) {
  unsigned u = __builtin_bit_cast(unsigned, f);
  unsigned r = (u + 0x7fffu + ((u >> 16) & 1u)) >> 16;
  return (unsigned short)r;
}

__device__ __forceinline__ void gl_lds16(const void* g, void* l) {
  __builtin_amdgcn_global_load_lds(
      (const __attribute__((address_space(1))) unsigned int*)g,
      (__attribute__((address_space(3))) unsigned int*)l, 16, 0, 0);
}

// ---------- fused prep: cvt W1->bf16 | v via atomicAdd | cbuf | gate+x->bf16 ----------
__global__ __launch_bounds__(256) void prep_kernel(
    const float* __restrict__ W1, unsigned short* __restrict__ w1bf,
    const float* __restrict__ W2, const float* __restrict__ W3,
    float* __restrict__ v,
    const float* __restrict__ b2, const float* __restrict__ b3,
    float* __restrict__ cbuf,
    const float* __restrict__ x, const float* __restrict__ Wg,
    unsigned short* __restrict__ xbf,
    float* __restrict__ wgt, float* __restrict__ base) {
  __shared__ float w3s[VD_CHUNK];
  const int b = blockIdx.x;

  if (b < CVT_BLOCKS) {
    size_t i = ((size_t)b * 256 + threadIdx.x) * 4;
    float4 f = *(const float4*)(W1 + i);
    ushort4 u;
    u.x = f2bf(f.x); u.y = f2bf(f.y); u.z = f2bf(f.z); u.w = f2bf(f.w);
    *(ushort4*)(w1bf + i) = u;
    return;
  }
  if (b < CVT_BLOCKS + VCALC_BLOCKS) {
    int vb = b - CVT_BLOCKS;          // 0..191
    int k  = vb / 96;
    int fb = (vb % 96) / 8;
    int db = vb % 8;
    if (threadIdx.x < VD_CHUNK) w3s[threadIdx.x] = W3[k*DDIM + db*VD_CHUNK + threadIdx.x];
    __syncthreads();
    int f = fb*256 + threadIdx.x;
    const float* W2k = W2 + (size_t)k*DDIM*FDIM + (size_t)db*VD_CHUNK*FDIM + f;
    float s = 0.f;
    #pragma unroll 8
    for (int d = 0; d < VD_CHUNK; ++d) s += W2k[(size_t)d*FDIM] * w3s[d];
    atomicAdd(&v[k*FDIM + f], s);
    return;
  }
  if (b == CVT_BLOCKS + VCALC_BLOCKS) {
    if (threadIdx.x < 128) {
      int k = threadIdx.x >> 6, lane = threadIdx.x & 63;
      float c = 0.f;
      #pragma unroll
      for (int it = 0; it < DDIM/64; ++it) {
        int i = it*64 + lane;
        c += b2[k*DDIM + i] * W3[k*DDIM + i];
      }
      #pragma unroll
      for (int m = 1; m < 64; m <<= 1) c += __shfl_xor(c, m, 64);
      if (lane == 0) cbuf[k] = c + b3[k];
    }
    return;
  }
  int gb   = b - (CVT_BLOCKS + VCALC_BLOCKS + 1);
  int wid  = threadIdx.x >> 6;
  int lane = threadIdx.x & 63;
  int n = gb * 4 + wid;
  const float4* xr = (const float4*)(x + (size_t)n * DDIM);
  ushort4* xw = (ushort4*)(xbf + (size_t)n * DDIM);
  float acc[8] = {0,0,0,0,0,0,0,0};
  float d30 = 0.f, d31 = 0.f;
  #pragma unroll
  for (int it = 0; it < DDIM/256; ++it) {
    int i = it*64 + lane;
    float4 xv = xr[i];
    ushort4 u;
    u.x = f2bf(xv.x); u.y = f2bf(xv.y); u.z = f2bf(xv.z); u.w = f2bf(xv.w);
    xw[i] = u;
    #pragma unroll
    for (int e = 0; e < 8; ++e) {
      float4 w = ((const float4*)(Wg + e*DDIM))[i];
      acc[e] += xv.x*w.x + xv.y*w.y + xv.z*w.z + xv.w*w.w;
    }
    float4 wa = ((const float4*)W3)[i];
    d30 += xv.x*wa.x + xv.y*wa.y + xv.z*wa.z + xv.w*wa.w;
    float4 wb = ((const float4*)(W3 + DDIM))[i];
    d31 += xv.x*wb.x + xv.y*wb.y + xv.z*wb.z + xv.w*wb.w;
  }
  #pragma unroll
  for (int m = 1; m < 64; m <<= 1) {
    #pragma unroll
    for (int e = 0; e < 8; ++e) acc[e] += __shfl_xor(acc[e], m, 64);
    d30 += __shfl_xor(d30, m, 64);
    d31 += __shfl_xor(d31, m, 64);
  }
  if (lane == 0) {
    float l1 = acc[0]; int a1 = 0;
    #pragma unroll
    for (int e = 1; e < 8; ++e) if (acc[e] > l1) { l1 = acc[e]; a1 = e; }
    float l2 = -3.4e38f;
    #pragma unroll
    for (int e = 0; e < 8; ++e) if (e != a1 && acc[e] > l2) l2 = acc[e];
    float w0 = 1.f / (1.f + __expf(l2 - l1));
    float w1 = 1.f - w0;
    wgt[2*n]   = w0;
    wgt[2*n+1] = w1;
    base[n] = w0 * d30 + w1 * d31;
  }
}

// ---------- fused GEMM, 256x256 tile, BK=32, half-tile software pipeline ----------
// part[bn][row] = sum_{col in tile bn(256)} relu(X@W1cat^T + b1)[row][col] * v[col]
// LDS: 4 buffers x 32KB (A 16KB: blocks 0-15, B 16KB: blocks 16-31). Fragment-order
// layout: block bb (1KB) holds G[bb*16 + (lane&15)][kslot lane>>4] at offset lane*16
// -> all ds_read_b128 stride-1 conflict-free.
// NEW MECHANISM vs R1-R8 (all pinned at 34% MfmaUtil): reads for half h+1 are issued
// BEFORE the MFMA cluster of half h; counted lgkmcnt waits only for half h's frags,
// so the next 4-8 ds_reads drain UNDER every 16-MFMA cluster (within-wave LDS/MFMA
// overlap). One barrier per K-tile. vmcnt(4) keeps 2 staged tiles in flight.
// Overwrite proof: stage(t+2) -> buf[(t+2)&3] overwrites buf(t-2); all reads of
// buf(t-2) completed before barrier(t-1) (lgkmcnt(0) precedes every barrier, and it
// is free because fa1 drained under MFMA h0).
__global__ __launch_bounds__(512, 2) void gemm_kernel(
    const unsigned short* __restrict__ A,   // 32768 x 768 bf16
    const unsigned short* __restrict__ B,   // 6144 x 768 bf16 (B^T layout)
    const float* __restrict__ b1,
    const float* __restrict__ v,
    float* __restrict__ part) {             // 24 x 32768
  __shared__ __align__(16) char smem[131072];   // 4 x 32KB

  const int tid  = threadIdx.x;
  const int lane = tid & 63, wid = tid >> 6;
  const int wm = wid >> 2, wn = wid & 3;        // 2M x 4N waves, per-wave C = 128x64
  const int q  = lane >> 4, cl = lane & 15;
  const int bn = blockIdx.x;     // 0..23
  const int bm = blockIdx.y;     // 0..127

  const unsigned short* Ab = A + (size_t)bm * 256 * DDIM;
  const unsigned short* Bb = B + (size_t)bn * 256 * DDIM;

  // staging source: thread (wid,lane) of round j fetches G[(j*8+wid)*16 + cl][kslot q]
  // -> lands (linear dest) at fragment block (j*8+wid), offset lane*16.
  const size_t srow = (size_t)(wid*16 + cl) * DDIM + q*8;

  const int lb = lane * 16;
  const int aOff = wm*8192 + lb;            // A block wm*8+m at +m*1024; fa1 at +4096
  const int bOff = 16384 + wn*4096 + lb;    // B block wn*4+n at +n*1024

  f32x4 zero = {0.f, 0.f, 0.f, 0.f};
  f32x4 acc[8][4];
  #pragma unroll
  for (int i = 0; i < 8; ++i)
    #pragma unroll
    for (int j = 0; j < 4; ++j) acc[i][j] = zero;

  auto stage = [&](int u) {
    char* d = smem + (u & 3) * 32768;
    const unsigned short* sA = Ab + srow + u*BK;
    gl_lds16(sA,            d + wid*1024);
    gl_lds16(sA + 128*DDIM, d + 8192 + wid*1024);
    const unsigned short* sB = Bb + srow + u*BK;
    gl_lds16(sB,            d + 16384 + wid*1024);
    gl_lds16(sB + 128*DDIM, d + 24576 + wid*1024);
  };

  bf16x8 fa0[2][4], fb[2][4], fa1[4];

  // prologue: tiles 0,1 staged; buf0 ready; issue reads(0,h0)
  stage(0);
  stage(1);
  asm volatile("s_waitcnt vmcnt(4)" ::: "memory");
  __builtin_amdgcn_s_barrier();
  __builtin_amdgcn_sched_barrier(0);
  {
    const char* c0 = smem;
    #pragma unroll
    for (int n = 0; n < 4; ++n) fb[0][n]  = *(const bf16x8*)(c0 + bOff + n*1024);
    #pragma unroll
    for (int m = 0; m < 4; ++m) fa0[0][m] = *(const bf16x8*)(c0 + aOff + m*1024);
  }

  #pragma unroll
  for (int t = 0; t < KTILES; ++t) {
    const int p = t & 1;
    const char* ct = smem + (t & 3) * 32768;

    // reads(t, h1) -> fa1 (drain under MFMA h0)
    #pragma unroll
    for (int m = 0; m < 4; ++m) fa1[m] = *(const bf16x8*)(ct + aOff + 4096 + m*1024);
    asm volatile("s_waitcnt lgkmcnt(4)" ::: "memory");   // fa0[p], fb[p] complete
    __builtin_amdgcn_sched_barrier(0);
    __builtin_amdgcn_s_setprio(1);
    #pragma unroll
    for (int m = 0; m < 4; ++m)
      #pragma unroll
      for (int n = 0; n < 4; ++n)
        acc[m][n] = __builtin_amdgcn_mfma_f32_16x16x32_bf16(fa0[p][m], fb[p][n], acc[m][n], 0, 0, 0);
    __builtin_amdgcn_s_setprio(0);

    if (t + 2 < KTILES) stage(t + 2);   // overwrites buf(t-2): reads done pre-barrier(t-1)

    if (t < KTILES - 1) {
      asm volatile("s_waitcnt lgkmcnt(0)" ::: "memory");   // fa1 drained (free)
      if (t + 2 < KTILES) { asm volatile("s_waitcnt vmcnt(4)" ::: "memory"); }
      else                { asm volatile("s_waitcnt vmcnt(0)" ::: "memory"); }
      __builtin_amdgcn_s_barrier();                        // buf(t+1) globally ready
      __builtin_amdgcn_sched_barrier(0);
      // reads(t+1, h0) -> fa0[p^1], fb[p^1] (drain under MFMA h1)
      const char* cn = smem + ((t + 1) & 3) * 32768;
      #pragma unroll
      for (int n = 0; n < 4; ++n) fb[p^1][n]  = *(const bf16x8*)(cn + bOff + n*1024);
      #pragma unroll
      for (int m = 0; m < 4; ++m) fa0[p^1][m] = *(const bf16x8*)(cn + aOff + m*1024);
      __builtin_amdgcn_s_setprio(1);
      #pragma unroll
      for (int m = 0; m < 4; ++m)
        #pragma unroll
        for (int n = 0; n < 4; ++n)
          acc[4 + m][n] = __builtin_amdgcn_mfma_f32_16x16x32_bf16(fa1[m], fb[p][n], acc[4 + m][n], 0, 0, 0);
      __builtin_amdgcn_s_setprio(0);
    } else {
      asm volatile("s_waitcnt lgkmcnt(0)" ::: "memory");
      __builtin_amdgcn_sched_barrier(0);
      __builtin_amdgcn_s_setprio(1);
      #pragma unroll
      for (int m = 0; m < 4; ++m)
        #pragma unroll
        for (int n = 0; n < 4; ++n)
          acc[4 + m][n] = __builtin_amdgcn_mfma_f32_16x16x32_bf16(fa1[m], fb[p][n], acc[4 + m][n], 0, 0, 0);
      __builtin_amdgcn_s_setprio(0);
    }
  }

  // epilogue: relu(acc + b1[col]) * v[col], reduce 256 cols per row
  float vv[4], bb[4];
  #pragma unroll
  for (int n = 0; n < 4; ++n) {
    int cg = bn*256 + wn*64 + n*16 + cl;
    vv[n] = v[cg];
    bb[n] = b1[cg];
  }
  float* red = (float*)smem;   // 4KB at smem+0 (all LDS reads retired by loop barriers)
  #pragma unroll
  for (int mt = 0; mt < 8; ++mt) {
    #pragma unroll
    for (int rr = 0; rr < 4; ++rr) {
      float s = 0.f;
      #pragma unroll
      for (int n = 0; n < 4; ++n) {
        float val = acc[mt][n][rr] + bb[n];
        s += fmaxf(val, 0.f) * vv[n];
      }
      #pragma unroll
      for (int msk = 1; msk < 16; msk <<= 1) s += __shfl_xor(s, msk, 64);
      if (cl == 0) red[(wm*128 + mt*16 + q*4 + rr)*4 + wn] = s;
    }
  }
  __syncthreads();
  if (tid < 256) {
    float r4 = red[tid*4] + red[tid*4+1] + red[tid*4+2] + red[tid*4+3];
    part[(size_t)bn * N_TOK + (size_t)bm*256 + tid] = r4;
  }
}

// ---------- final combine (adds the cbuf term moved out of gate) ----------
__global__ __launch_bounds__(256) void final_kernel(const float* __restrict__ part,
                                                    const float* __restrict__ wgt,
                                                    const float* __restrict__ base,
                                                    const float* __restrict__ cbuf,
                                                    float* __restrict__ out) {
  int n = blockIdx.x * 256 + threadIdx.x;
  float s0 = 0.f, s1 = 0.f;
  #pragma unroll
  for (int t = 0; t < 12; ++t) s0 += part[(size_t)t*N_TOK + n];
  #pragma unroll
  for (int t = 12; t < 24; ++t) s1 += part[(size_t)t*N_TOK + n];
  out[n] = base[n] + wgt[2*n]*(s0 + cbuf[0]) + wgt[2*n+1]*(s1 + cbuf[1]);
}

extern "C" void kernel_launch(void* const* d_in, const int* in_sizes, int n_in,
                              void* d_out, int out_size, void* d_ws, size_t ws_size,
                              hipStream_t stream) {
  const float* x  = (const float*)d_in[0];
  const float* Wg = (const float*)d_in[1];
  const float* W1 = (const float*)d_in[2];
  const float* b1 = (const float*)d_in[3];
  const float* W2 = (const float*)d_in[4];
  const float* b2 = (const float*)d_in[5];
  const float* W3 = (const float*)d_in[6];
  const float* b3 = (const float*)d_in[7];
  float* out = (float*)d_out;

  char* ws = (char*)d_ws;
  size_t off = 0;
  auto alloc = [&](size_t bytes) -> char* {
    char* p = ws + off;
    off += (bytes + 255) & ~(size_t)255;
    return p;
  };
  unsigned short* xbf  = (unsigned short*)alloc((size_t)N_TOK * DDIM * 2);   // 48 MB
  unsigned short* w1bf = (unsigned short*)alloc((size_t)NCOLS * DDIM * 2);   // 9 MB
  float* v     = (float*)alloc((size_t)NCOLS * 4);
  float* cbuf  = (float*)alloc(64);
  float* wgt   = (float*)alloc((size_t)N_TOK * 2 * 4);
  float* base  = (float*)alloc((size_t)N_TOK * 4);
  float* part  = (float*)alloc((size_t)NTILES * N_TOK * 4);                  // 3.1 MB
  if (off > ws_size) return;

  hipMemsetAsync(v, 0, (size_t)NCOLS * 4, stream);
  prep_kernel<<<PREP_BLOCKS, 256, 0, stream>>>(W1, w1bf, W2, W3, v, b2, b3, cbuf,
                                               x, Wg, xbf, wgt, base);
  gemm_kernel<<<dim3(NTILES, N_TOK/256), 512, 0, stream>>>(xbf, w1bf, b1, v, part);
  final_kernel<<<N_TOK/256, 256, 0, stream>>>(part, wgt, base, cbuf, out);
}